// Round 1
// baseline (884.165 us; speedup 1.0000x reference)
//
#include <hip/hip_runtime.h>
#include <math.h>

#define NN 8192
#define EE 262144
#define GG 64
#define CC 10
#define KK1 4096
#define KK2 2048
#define KK3 1024

__device__ __forceinline__ float eluf(float x) { return x > 0.f ? x : expm1f(x); }
__device__ __forceinline__ float sigf(float x) { return 1.f / (1.f + expf(-x)); }
__device__ __forceinline__ unsigned f2s(float f) {
    unsigned u = __float_as_uint(f);
    return (u & 0x80000000u) ? ~u : (u | 0x80000000u);
}
__device__ __forceinline__ float s2f(unsigned u) {
    return (u & 0x80000000u) ? __uint_as_float(u ^ 0x80000000u) : __uint_as_float(~u);
}

// ---- edge init: dedup representative flag + weighted in-degree (level 1) ----
__global__ void k_edge_init(const int* __restrict__ ei, unsigned* __restrict__ bitmap,
                            unsigned char* __restrict__ rep, int* __restrict__ cnt1) {
    int e = blockIdx.x * blockDim.x + threadIdx.x;
    if (e >= EE) return;
    int s = ei[e], d = ei[EE + e];
    unsigned key = ((unsigned)s << 13) | (unsigned)d;   // N = 8192 = 2^13
    unsigned old = atomicOr(&bitmap[key >> 5], 1u << (key & 31u));
    rep[e] = ((old >> (key & 31u)) & 1u) ? 0 : 1;
    atomicAdd(&cnt1[d], 1);
}

__global__ void k_dinv(const int* __restrict__ cnt, float* __restrict__ dinv, int n) {
    int j = blockIdx.x * blockDim.x + threadIdx.x;
    if (j < n) dinv[j] = 1.f / sqrtf((float)(cnt[j] + 1));
}

// ---- Y[m,f] = sum_k X[m,k] * W[k,f] ----
__global__ void k_mm(const float* __restrict__ X, const float* __restrict__ W,
                     float* __restrict__ Y, int M, int K, int F) {
    int t = blockIdx.x * blockDim.x + threadIdx.x;
    if (t >= M * F) return;
    int m = t / F, f = t - m * F;
    const float* xr = X + (size_t)m * K;
    float s = 0.f;
    for (int k = 0; k < K; k += 4) {
        s += xr[k] * W[k * F + f];
        s += xr[k + 1] * W[(k + 1) * F + f];
        s += xr[k + 2] * W[(k + 2) * F + f];
        s += xr[k + 3] * W[(k + 3) * F + f];
    }
    Y[t] = s;
}

// ---- acc[r,f] = dinv[r]^2 * xW[r,f]  (identity term of Ah = A + I) ----
__global__ void k_self(const float* __restrict__ dinv, const float* __restrict__ xW,
                       float* __restrict__ acc, int total, int logF) {
    int t = blockIdx.x * blockDim.x + threadIdx.x;
    if (t >= total) return;
    int r = t >> logF;
    float dv = dinv[r];
    acc[t] = dv * dv * xW[t];
}

// ---- level-1 propagate: all edges, with multiplicity ----
__global__ void k_prop_l1(const int* __restrict__ ei, const float* __restrict__ dinv,
                          const float* __restrict__ xW, float* __restrict__ acc, int logF) {
    int t = blockIdx.x * blockDim.x + threadIdx.x;
    if (t >= (EE << logF)) return;
    int e = t >> logF, f = t & ((1 << logF) - 1);
    int s = ei[e], d = ei[EE + e];
    atomicAdd(&acc[(d << logF) + f], dinv[s] * dinv[d] * xW[(s << logF) + f]);
}

// ---- compact active (dedup'd, both-endpoints-selected) edges for a pooled level ----
__global__ void k_compact(const int* __restrict__ ei, const unsigned char* __restrict__ rep,
                          const int* __restrict__ pos, unsigned* __restrict__ elist,
                          int* __restrict__ count) {
    int e = blockIdx.x * blockDim.x + threadIdx.x;
    if (e >= EE || !rep[e]) return;
    int ps = pos[ei[e]], pd = pos[ei[EE + e]];
    if (ps >= 0 && pd >= 0) {
        int i = atomicAdd(count, 1);
        elist[i] = ((unsigned)ps << 16) | (unsigned)pd;
    }
}

__global__ void k_deg_pool(const unsigned* __restrict__ elist, const int* __restrict__ count,
                           int* __restrict__ cnt) {
    int n = *count;
    for (int t = blockIdx.x * blockDim.x + threadIdx.x; t < n; t += gridDim.x * blockDim.x)
        atomicAdd(&cnt[elist[t] & 0xFFFFu], 1);
}

__global__ void k_prop_pool(const unsigned* __restrict__ elist, const int* __restrict__ count,
                            const float* __restrict__ dinv, const float* __restrict__ xW,
                            float* __restrict__ acc, int logF) {
    int total = (*count) << logF;
    int mask = (1 << logF) - 1;
    for (int t = blockIdx.x * blockDim.x + threadIdx.x; t < total; t += gridDim.x * blockDim.x) {
        int e = t >> logF, f = t & mask;
        unsigned pk = elist[e];
        int ps = pk >> 16, pd = pk & 0xFFFFu;
        atomicAdd(&acc[(pd << logF) + f], dinv[ps] * dinv[pd] * xW[(ps << logF) + f]);
    }
}

// ---- x[t] = elu(acc[t] + b[f]) ----
__global__ void k_epi(const float* __restrict__ acc, const float* __restrict__ b,
                      float* __restrict__ x, int total, int mask) {
    int t = blockIdx.x * blockDim.x + threadIdx.x;
    if (t >= total) return;
    x[t] = eluf(acc[t] + b[t & mask]);
}

// ---- score[r] = dot(x[r], p) / ||p|| ----
__global__ void k_score(const float* __restrict__ x, const float* __restrict__ p,
                        int n, int F, float* __restrict__ score) {
    int r = blockIdx.x * blockDim.x + threadIdx.x;
    if (r >= n) return;
    float nrm = 0.f, dp = 0.f;
    const float* xr = x + (size_t)r * F;
    for (int k = 0; k < F; k++) { nrm += p[k] * p[k]; dp += xr[k] * p[k]; }
    score[r] = dp / sqrtf(nrm);
}

// ---- exact top-k: single-block bitonic sort, descending, ties -> smaller index ----
__global__ void k_topk(const float* __restrict__ score, int n, int k, int* __restrict__ out_idx) {
    __shared__ unsigned long long keys[8192];
    int tid = threadIdx.x;
    for (int i = tid; i < n; i += blockDim.x) {
        unsigned su = f2s(score[i]);
        keys[i] = ((unsigned long long)su << 32) | (unsigned)(~i);
    }
    __syncthreads();
    for (int sz = 2; sz <= n; sz <<= 1) {
        for (int st = sz >> 1; st > 0; st >>= 1) {
            for (int i = tid; i < n; i += blockDim.x) {
                int j = i ^ st;
                if (j > i) {
                    unsigned long long a = keys[i], b = keys[j];
                    bool up = ((i & sz) == 0);           // descending overall
                    if (up ? (a < b) : (a > b)) { keys[i] = b; keys[j] = a; }
                }
            }
            __syncthreads();
        }
    }
    for (int r = tid; r < k; r += blockDim.x)
        out_idx[r] = (int)(~(unsigned)(keys[r] & 0xFFFFFFFFu));
}

__global__ void k_pos2(const int* __restrict__ i2, int* __restrict__ pos2) {
    int r = blockIdx.x * blockDim.x + threadIdx.x;
    if (r < KK1) pos2[i2[r]] = r;
}
__global__ void k_pos3(const int* __restrict__ i2, const int* __restrict__ i4,
                       int* __restrict__ pos3) {
    int q = blockIdx.x * blockDim.x + threadIdx.x;
    if (q < KK2) pos3[i2[i4[q]]] = q;
}
__global__ void k_pos4(const int* __restrict__ i2, const int* __restrict__ i4,
                       const int* __restrict__ i6, int* __restrict__ pos4) {
    int r = blockIdx.x * blockDim.x + threadIdx.x;
    if (r < KK3) pos4[i2[i4[i6[r]]]] = r;
}

// ---- pooled features: xout[r] = elu(x[idx[r]] * sigmoid(score[idx[r]])) ----
__global__ void k_poolx(const float* __restrict__ x, const float* __restrict__ score,
                        const int* __restrict__ idx, int k, int F, float* __restrict__ xout) {
    int t = blockIdx.x * blockDim.x + threadIdx.x;
    if (t >= k * F) return;
    int r = t / F, f = t - r * F;
    int j = idx[r];
    xout[t] = eluf(x[(size_t)j * F + f] * sigf(score[j]));
}

// ---- unpool scatter (left part of concat), with elu ----
__global__ void k_scat(const float* __restrict__ xin, const int* __restrict__ idx,
                       float* __restrict__ xcat, int k, int Fl, int Fcat) {
    int t = blockIdx.x * blockDim.x + threadIdx.x;
    if (t >= k * Fl) return;
    int r = t / Fl, f = t - r * Fl;
    xcat[(size_t)idx[r] * Fcat + f] = eluf(xin[t]);
}
// ---- right part of concat, with elu ----
__global__ void k_catr(const float* __restrict__ xr, float* __restrict__ xcat,
                       int n, int Fr, int Fcat, int off) {
    int t = blockIdx.x * blockDim.x + threadIdx.x;
    if (t >= n * Fr) return;
    int q = t / Fr, f = t - q * Fr;
    xcat[(size_t)q * Fcat + off + f] = eluf(xr[t]);
}

// ---- segment max/sum/count over batch ----
__global__ void k_seg(const float* __restrict__ x13, const int* __restrict__ batch,
                      unsigned* __restrict__ gmaxu, float* __restrict__ gsum,
                      int* __restrict__ gcnt) {
    int t = blockIdx.x * blockDim.x + threadIdx.x;
    if (t >= NN * 32) return;
    int j = t >> 5, f = t & 31;
    int g = batch[j];
    float v = x13[t];
    atomicMax(&gmaxu[(g << 5) + f], f2s(v));
    atomicAdd(&gsum[(g << 5) + f], v);
    if (f == 0) atomicAdd(&gcnt[g], 1);
}

// ---- head: h0 = elu([gmax, gmean]); h1 = elu(h0@Wl1); out = log_softmax(h1@Wc + bc) ----
__global__ void k_head(const unsigned* __restrict__ gmaxu, const float* __restrict__ gsum,
                       const int* __restrict__ gcnt, const float* __restrict__ Wl1,
                       const float* __restrict__ Wc, const float* __restrict__ bc,
                       float* __restrict__ out) {
    __shared__ float h0[GG * 64];
    __shared__ float h1[GG * 64];
    __shared__ float lg[GG * CC];
    int tid = threadIdx.x;
    for (int t = tid; t < GG * 64; t += blockDim.x) {
        int g = t >> 6, c = t & 63;
        float v;
        if (c < 32) v = s2f(gmaxu[(g << 5) + c]);
        else v = gsum[(g << 5) + (c - 32)] / (float)gcnt[g];
        h0[t] = eluf(v);
    }
    __syncthreads();
    for (int t = tid; t < GG * 64; t += blockDim.x) {
        int g = t >> 6, j = t & 63;
        float s = 0.f;
        for (int k = 0; k < 64; k++) s += h0[(g << 6) + k] * Wl1[k * 64 + j];
        h1[t] = eluf(s);
    }
    __syncthreads();
    for (int t = tid; t < GG * CC; t += blockDim.x) {
        int g = t / CC, c = t - g * CC;
        float s = bc[c];
        for (int k = 0; k < 64; k++) s += h1[(g << 6) + k] * Wc[k * CC + c];
        lg[t] = s;
    }
    __syncthreads();
    if (tid < GG) {
        int g = tid;
        float m = -1e30f;
        for (int c = 0; c < CC; c++) m = fmaxf(m, lg[g * CC + c]);
        float se = 0.f;
        for (int c = 0; c < CC; c++) se += expf(lg[g * CC + c] - m);
        float lse = m + logf(se);
        for (int c = 0; c < CC; c++) out[g * CC + c] = lg[g * CC + c] - lse;
    }
}

extern "C" void kernel_launch(void* const* d_in, const int* in_sizes, int n_in,
                              void* d_out, int out_size, void* d_ws, size_t ws_size,
                              hipStream_t stream) {
    const float* x = (const float*)d_in[0];
    const int* ei = (const int*)d_in[1];
    const int* batch = (const int*)d_in[2];
    const float* W1 = (const float*)d_in[3];  const float* b1 = (const float*)d_in[4];
    const float* W2 = (const float*)d_in[5];  const float* b2 = (const float*)d_in[6];
    const float* W3 = (const float*)d_in[7];  const float* b3 = (const float*)d_in[8];
    const float* W4 = (const float*)d_in[9];  const float* b4 = (const float*)d_in[10];
    const float* W5 = (const float*)d_in[11]; const float* b5 = (const float*)d_in[12];
    const float* W6 = (const float*)d_in[13]; const float* b6 = (const float*)d_in[14];
    const float* W7 = (const float*)d_in[15]; const float* b7 = (const float*)d_in[16];
    const float* p1 = (const float*)d_in[17];
    const float* p2 = (const float*)d_in[18];
    const float* p3 = (const float*)d_in[19];
    const float* Wl1 = (const float*)d_in[20];
    const float* Wc = (const float*)d_in[21];
    const float* bc = (const float*)d_in[22];
    float* out = (float*)d_out;
    (void)in_sizes; (void)n_in; (void)out_size; (void)ws_size;

    char* w = (char*)d_ws;
    size_t off = 0;
    auto alloc = [&](size_t bytes) -> char* {
        char* p = w + off;
        off = (off + bytes + 255) & ~(size_t)255;
        return p;
    };

    // ---- zero-initialized span ----
    size_t zero_begin = off;
    unsigned* bitmap = (unsigned*)alloc((size_t)NN * NN / 8);       // 8 MB
    int* cnt1 = (int*)alloc(NN * 4);
    int* cnt2 = (int*)alloc(KK1 * 4);
    int* cnt3 = (int*)alloc(KK2 * 4);
    int* cnt4 = (int*)alloc(KK3 * 4);
    int* ecnt2 = (int*)alloc(4);
    int* ecnt3 = (int*)alloc(4);
    int* ecnt4 = (int*)alloc(4);
    unsigned* gmaxu = (unsigned*)alloc(GG * 32 * 4);
    float* gsum = (float*)alloc(GG * 32 * 4);
    int* gcnt = (int*)alloc(GG * 4);
    float* x8 = (float*)alloc((size_t)KK2 * 384 * 4);
    float* x10 = (float*)alloc((size_t)KK1 * 192 * 4);
    float* x12 = (float*)alloc((size_t)NN * 96 * 4);
    size_t zero_len = off - zero_begin;

    // ---- 0xFF-initialized span (pos arrays = -1) ----
    size_t ff_begin = off;
    int* pos2 = (int*)alloc(NN * 4);
    int* pos3 = (int*)alloc(NN * 4);
    int* pos4 = (int*)alloc(NN * 4);
    size_t ff_len = off - ff_begin;

    // ---- uninitialized scratch ----
    unsigned char* rep = (unsigned char*)alloc(EE);
    float* dinv1 = (float*)alloc(NN * 4);
    float* dinv2 = (float*)alloc(KK1 * 4);
    float* dinv3 = (float*)alloc(KK2 * 4);
    float* dinv4 = (float*)alloc(KK3 * 4);
    float* xW = (float*)alloc((size_t)262144 * 4);   // max M*F = 262144 for all matmuls
    float* acc = (float*)alloc((size_t)262144 * 4);
    float* x1 = (float*)alloc((size_t)NN * 32 * 4);
    float* x2 = (float*)alloc((size_t)KK1 * 32 * 4);
    float* x3 = (float*)alloc((size_t)KK1 * 64 * 4);
    float* x4 = (float*)alloc((size_t)KK2 * 64 * 4);
    float* x5 = (float*)alloc((size_t)KK2 * 128 * 4);
    float* x6 = (float*)alloc((size_t)KK3 * 128 * 4);
    float* x7 = (float*)alloc((size_t)KK3 * 256 * 4);
    float* x9 = (float*)alloc((size_t)KK2 * 128 * 4);
    float* x11 = (float*)alloc((size_t)KK1 * 64 * 4);
    float* x13 = (float*)alloc((size_t)NN * 32 * 4);
    float* score1 = (float*)alloc(NN * 4);
    float* score2 = (float*)alloc(KK1 * 4);
    float* score3 = (float*)alloc(KK2 * 4);
    int* i2 = (int*)alloc(KK1 * 4);
    int* i4 = (int*)alloc(KK2 * 4);
    int* i6 = (int*)alloc(KK3 * 4);
    unsigned* elist2 = (unsigned*)alloc((size_t)EE * 4);
    unsigned* elist3 = (unsigned*)alloc((size_t)EE * 4);
    unsigned* elist4 = (unsigned*)alloc((size_t)EE * 4);

    hipMemsetAsync(w + zero_begin, 0, zero_len, stream);
    hipMemsetAsync(w + ff_begin, 0xFF, ff_len, stream);

    const int B = 256;
    // ---- setup: dedup flags + weighted level-1 degree ----
    k_edge_init<<<EE / B, B, 0, stream>>>(ei, bitmap, rep, cnt1);
    k_dinv<<<NN / B, B, 0, stream>>>(cnt1, dinv1, NN);

    // ---- gcn1: x1 = elu(gcn(A, x, W1, b1)) ----
    k_mm<<<(NN * 32) / B, B, 0, stream>>>(x, W1, xW, NN, 128, 32);
    k_self<<<(NN * 32) / B, B, 0, stream>>>(dinv1, xW, acc, NN * 32, 5);
    k_prop_l1<<<(EE * 32) / B, B, 0, stream>>>(ei, dinv1, xW, acc, 5);
    k_epi<<<(NN * 32) / B, B, 0, stream>>>(acc, b1, x1, NN * 32, 31);

    // ---- pool1: top-4096 ----
    k_score<<<NN / B, B, 0, stream>>>(x1, p1, NN, 32, score1);
    k_topk<<<1, 1024, 0, stream>>>(score1, NN, KK1, i2);
    k_pos2<<<KK1 / B, B, 0, stream>>>(i2, pos2);
    k_poolx<<<(KK1 * 32) / B, B, 0, stream>>>(x1, score1, i2, KK1, 32, x2);
    k_compact<<<EE / B, B, 0, stream>>>(ei, rep, pos2, elist2, ecnt2);
    k_deg_pool<<<256, B, 0, stream>>>(elist2, ecnt2, cnt2);
    k_dinv<<<KK1 / B, B, 0, stream>>>(cnt2, dinv2, KK1);

    // ---- gcn2: x3 ----
    k_mm<<<(KK1 * 64) / B, B, 0, stream>>>(x2, W2, xW, KK1, 32, 64);
    k_self<<<(KK1 * 64) / B, B, 0, stream>>>(dinv2, xW, acc, KK1 * 64, 6);
    k_prop_pool<<<1024, B, 0, stream>>>(elist2, ecnt2, dinv2, xW, acc, 6);
    k_epi<<<(KK1 * 64) / B, B, 0, stream>>>(acc, b2, x3, KK1 * 64, 63);

    // ---- pool2: top-2048 ----
    k_score<<<KK1 / B, B, 0, stream>>>(x3, p2, KK1, 64, score2);
    k_topk<<<1, 1024, 0, stream>>>(score2, KK1, KK2, i4);
    k_pos3<<<KK2 / B, B, 0, stream>>>(i2, i4, pos3);
    k_poolx<<<(KK2 * 64) / B, B, 0, stream>>>(x3, score2, i4, KK2, 64, x4);
    k_compact<<<EE / B, B, 0, stream>>>(ei, rep, pos3, elist3, ecnt3);
    k_deg_pool<<<256, B, 0, stream>>>(elist3, ecnt3, cnt3);
    k_dinv<<<KK2 / B, B, 0, stream>>>(cnt3, dinv3, KK2);

    // ---- gcn3: x5 ----
    k_mm<<<(KK2 * 128) / B, B, 0, stream>>>(x4, W3, xW, KK2, 64, 128);
    k_self<<<(KK2 * 128) / B, B, 0, stream>>>(dinv3, xW, acc, KK2 * 128, 7);
    k_prop_pool<<<1024, B, 0, stream>>>(elist3, ecnt3, dinv3, xW, acc, 7);
    k_epi<<<(KK2 * 128) / B, B, 0, stream>>>(acc, b3, x5, KK2 * 128, 127);

    // ---- pool3: top-1024 ----
    k_score<<<KK2 / B, B, 0, stream>>>(x5, p3, KK2, 128, score3);
    k_topk<<<1, 1024, 0, stream>>>(score3, KK2, KK3, i6);
    k_pos4<<<KK3 / B, B, 0, stream>>>(i2, i4, i6, pos4);
    k_poolx<<<(KK3 * 128) / B, B, 0, stream>>>(x5, score3, i6, KK3, 128, x6);
    k_compact<<<EE / B, B, 0, stream>>>(ei, rep, pos4, elist4, ecnt4);
    k_deg_pool<<<256, B, 0, stream>>>(elist4, ecnt4, cnt4);
    k_dinv<<<KK3 / B, B, 0, stream>>>(cnt4, dinv4, KK3);

    // ---- gcn4: x7 ----
    k_mm<<<(KK3 * 256) / B, B, 0, stream>>>(x6, W4, xW, KK3, 128, 256);
    k_self<<<(KK3 * 256) / B, B, 0, stream>>>(dinv4, xW, acc, KK3 * 256, 8);
    k_prop_pool<<<1024, B, 0, stream>>>(elist4, ecnt4, dinv4, xW, acc, 8);
    k_epi<<<(KK3 * 256) / B, B, 0, stream>>>(acc, b4, x7, KK3 * 256, 255);

    // ---- unpool -> x8 = elu(concat([scatter(x7, i6), x5])) at L3 ----
    k_scat<<<(KK3 * 256) / B, B, 0, stream>>>(x7, i6, x8, KK3, 256, 384);
    k_catr<<<(KK2 * 128) / B, B, 0, stream>>>(x5, x8, KK2, 128, 384, 256);

    // ---- gcn5: x9 ----
    k_mm<<<(KK2 * 128) / B, B, 0, stream>>>(x8, W5, xW, KK2, 384, 128);
    k_self<<<(KK2 * 128) / B, B, 0, stream>>>(dinv3, xW, acc, KK2 * 128, 7);
    k_prop_pool<<<1024, B, 0, stream>>>(elist3, ecnt3, dinv3, xW, acc, 7);
    k_epi<<<(KK2 * 128) / B, B, 0, stream>>>(acc, b5, x9, KK2 * 128, 127);

    // ---- unpool -> x10 at L2 ----
    k_scat<<<(KK2 * 128) / B, B, 0, stream>>>(x9, i4, x10, KK2, 128, 192);
    k_catr<<<(KK1 * 64) / B, B, 0, stream>>>(x3, x10, KK1, 64, 192, 128);

    // ---- gcn6: x11 ----
    k_mm<<<(KK1 * 64) / B, B, 0, stream>>>(x10, W6, xW, KK1, 192, 64);
    k_self<<<(KK1 * 64) / B, B, 0, stream>>>(dinv2, xW, acc, KK1 * 64, 6);
    k_prop_pool<<<1024, B, 0, stream>>>(elist2, ecnt2, dinv2, xW, acc, 6);
    k_epi<<<(KK1 * 64) / B, B, 0, stream>>>(acc, b6, x11, KK1 * 64, 63);

    // ---- unpool -> x12 at L1 ----
    k_scat<<<(KK1 * 64) / B, B, 0, stream>>>(x11, i2, x12, KK1, 64, 96);
    k_catr<<<(NN * 32) / B, B, 0, stream>>>(x1, x12, NN, 32, 96, 64);

    // ---- gcn7: x13 (original weighted A) ----
    k_mm<<<(NN * 32) / B, B, 0, stream>>>(x12, W7, xW, NN, 96, 32);
    k_self<<<(NN * 32) / B, B, 0, stream>>>(dinv1, xW, acc, NN * 32, 5);
    k_prop_l1<<<(EE * 32) / B, B, 0, stream>>>(ei, dinv1, xW, acc, 5);
    k_epi<<<(NN * 32) / B, B, 0, stream>>>(acc, b7, x13, NN * 32, 31);

    // ---- readout ----
    k_seg<<<(NN * 32) / B, B, 0, stream>>>(x13, batch, gmaxu, gsum, gcnt);
    k_head<<<1, 1024, 0, stream>>>(gmaxu, gsum, gcnt, Wl1, Wc, bc, out);
}

// Round 2
// 713.489 us; speedup vs baseline: 1.2392x; 1.2392x over previous
//
#include <hip/hip_runtime.h>
#include <math.h>

#define NN 8192
#define EE 262144
#define GG 64
#define CC 10
#define KK1 4096
#define KK2 2048
#define KK3 1024

__device__ __forceinline__ float eluf(float x) { return x > 0.f ? x : expm1f(x); }
__device__ __forceinline__ float sigf(float x) { return 1.f / (1.f + expf(-x)); }
__device__ __forceinline__ unsigned f2s(float f) {
    unsigned u = __float_as_uint(f);
    return (u & 0x80000000u) ? ~u : (u | 0x80000000u);
}
__device__ __forceinline__ float s2f(unsigned u) {
    return (u & 0x80000000u) ? __uint_as_float(u ^ 0x80000000u) : __uint_as_float(~u);
}

// ---- edge init: dedup representative flag + weighted in-degree (level 1) ----
__global__ void k_edge_init(const int* __restrict__ ei, unsigned* __restrict__ bitmap,
                            unsigned char* __restrict__ rep, int* __restrict__ cnt1) {
    int e = blockIdx.x * blockDim.x + threadIdx.x;
    if (e >= EE) return;
    int s = ei[e], d = ei[EE + e];
    unsigned key = ((unsigned)s << 13) | (unsigned)d;   // N = 8192 = 2^13
    unsigned old = atomicOr(&bitmap[key >> 5], 1u << (key & 31u));
    rep[e] = ((old >> (key & 31u)) & 1u) ? 0 : 1;
    atomicAdd(&cnt1[d], 1);
}

__global__ void k_dinv(const int* __restrict__ cnt, float* __restrict__ dinv, int n) {
    int j = blockIdx.x * blockDim.x + threadIdx.x;
    if (j < n) dinv[j] = 1.f / sqrtf((float)(cnt[j] + 1));
}

// ---- Y[m,f] = sum_k X[m,k]*W[k,f]; acc[m,f] = dinv[m]^2 * Y[m,f] (self term fused) ----
__global__ void k_mm(const float* __restrict__ X, const float* __restrict__ W,
                     float* __restrict__ Y, const float* __restrict__ dinv,
                     float* __restrict__ acc, int M, int K, int F) {
    int t = blockIdx.x * blockDim.x + threadIdx.x;
    if (t >= M * F) return;
    int m = t / F, f = t - m * F;
    const float* xr = X + (size_t)m * K;
    float s = 0.f;
    for (int k = 0; k < K; k += 4) {
        s += xr[k] * W[k * F + f];
        s += xr[k + 1] * W[(k + 1) * F + f];
        s += xr[k + 2] * W[(k + 2) * F + f];
        s += xr[k + 3] * W[(k + 3) * F + f];
    }
    Y[t] = s;
    float dv = dinv[m];
    acc[t] = dv * dv * s;
}

// ---- level-1 propagate: all edges, with multiplicity ----
__global__ void k_prop_l1(const int* __restrict__ ei, const float* __restrict__ dinv,
                          const float* __restrict__ xW, float* __restrict__ acc, int logF) {
    int t = blockIdx.x * blockDim.x + threadIdx.x;
    if (t >= (EE << logF)) return;
    int e = t >> logF, f = t & ((1 << logF) - 1);
    int s = ei[e], d = ei[EE + e];
    atomicAdd(&acc[(d << logF) + f], dinv[s] * dinv[d] * xW[(s << logF) + f]);
}

// ---- compact active (dedup'd, both-endpoints-selected) edges for a pooled level ----
__global__ void k_compact(const int* __restrict__ ei, const unsigned char* __restrict__ rep,
                          const int* __restrict__ pos, unsigned* __restrict__ elist,
                          int* __restrict__ count) {
    int e = blockIdx.x * blockDim.x + threadIdx.x;
    if (e >= EE || !rep[e]) return;
    int ps = pos[ei[e]], pd = pos[ei[EE + e]];
    if (ps >= 0 && pd >= 0) {
        int i = atomicAdd(count, 1);
        elist[i] = ((unsigned)ps << 16) | (unsigned)pd;
    }
}

__global__ void k_deg_pool(const unsigned* __restrict__ elist, const int* __restrict__ count,
                           int* __restrict__ cnt) {
    int n = *count;
    for (int t = blockIdx.x * blockDim.x + threadIdx.x; t < n; t += gridDim.x * blockDim.x)
        atomicAdd(&cnt[elist[t] & 0xFFFFu], 1);
}

__global__ void k_prop_pool(const unsigned* __restrict__ elist, const int* __restrict__ count,
                            const float* __restrict__ dinv, const float* __restrict__ xW,
                            float* __restrict__ acc, int logF) {
    int total = (*count) << logF;
    int mask = (1 << logF) - 1;
    for (int t = blockIdx.x * blockDim.x + threadIdx.x; t < total; t += gridDim.x * blockDim.x) {
        int e = t >> logF, f = t & mask;
        unsigned pk = elist[e];
        int ps = pk >> 16, pd = pk & 0xFFFFu;
        atomicAdd(&acc[(pd << logF) + f], dinv[ps] * dinv[pd] * xW[(ps << logF) + f]);
    }
}

// ---- x[t] = elu(acc[t] + b[f]) ----
__global__ void k_epi(const float* __restrict__ acc, const float* __restrict__ b,
                      float* __restrict__ x, int total, int mask) {
    int t = blockIdx.x * blockDim.x + threadIdx.x;
    if (t >= total) return;
    x[t] = eluf(acc[t] + b[t & mask]);
}

// ---- score[r] = dot(x[r], p) / ||p|| ----
__global__ void k_score(const float* __restrict__ x, const float* __restrict__ p,
                        int n, int F, float* __restrict__ score) {
    int r = blockIdx.x * blockDim.x + threadIdx.x;
    if (r >= n) return;
    float nrm = 0.f, dp = 0.f;
    const float* xr = x + (size_t)r * F;
    for (int k = 0; k < F; k++) { nrm += p[k] * p[k]; dp += xr[k] * p[k]; }
    score[r] = dp / sqrtf(nrm);
}

// ==== parallel bitonic top-k (descending, ties -> smaller index; exact jax order) ====
// key = (sortable(score) << 32) | ~idx ; sort descending; dir rule: ((gi & sz)==0)

// chunk sort: each block sorts a 2048-key chunk in LDS (stages sz=2..2048)
__global__ void k_sort_chunk(const float* __restrict__ score,
                             unsigned long long* __restrict__ keys,
                             int last, int k, int* __restrict__ out_idx) {
    __shared__ unsigned long long sk[2048];
    int base = blockIdx.x << 11;
    int tid = threadIdx.x;
    for (int i = tid; i < 2048; i += 1024) {
        int gi = base + i;
        sk[i] = ((unsigned long long)f2s(score[gi]) << 32) | (unsigned)(~gi);
    }
    __syncthreads();
    for (int sz = 2; sz <= 2048; sz <<= 1) {
        for (int st = sz >> 1; st > 0; st >>= 1) {
            int i = ((tid & ~(st - 1)) << 1) | (tid & (st - 1));
            int j = i | st;
            unsigned long long a = sk[i], b = sk[j];
            bool desc = (((base + i) & sz) == 0);
            if (desc ? (a < b) : (a > b)) { sk[i] = b; sk[j] = a; }
            __syncthreads();
        }
    }
    if (last) {
        for (int i = tid; i < 2048; i += 1024) {
            int gi = base + i;
            if (gi < k) out_idx[gi] = (int)(~(unsigned)(sk[i] & 0xFFFFFFFFu));
        }
    } else {
        for (int i = tid; i < 2048; i += 1024) keys[base + i] = sk[i];
    }
}

// global compare-exchange pass for stride st >= 2048 of stage sz
__global__ void k_gpass(unsigned long long* __restrict__ keys, int sz, int st) {
    int p = blockIdx.x * blockDim.x + threadIdx.x;
    int i = ((p & ~(st - 1)) << 1) | (p & (st - 1));
    int j = i | st;
    unsigned long long a = keys[i], b = keys[j];
    bool desc = ((i & sz) == 0);
    if (desc ? (a < b) : (a > b)) { keys[i] = b; keys[j] = a; }
}

// local merge: strides 1024..1 of stage sz, per 2048-chunk in LDS
__global__ void k_lmerge(unsigned long long* __restrict__ keys, int sz,
                         int last, int k, int* __restrict__ out_idx) {
    __shared__ unsigned long long sk[2048];
    int base = blockIdx.x << 11;
    int tid = threadIdx.x;
    for (int i = tid; i < 2048; i += 1024) sk[i] = keys[base + i];
    __syncthreads();
    for (int st = 1024; st > 0; st >>= 1) {
        int i = ((tid & ~(st - 1)) << 1) | (tid & (st - 1));
        int j = i | st;
        unsigned long long a = sk[i], b = sk[j];
        bool desc = (((base + i) & sz) == 0);
        if (desc ? (a < b) : (a > b)) { sk[i] = b; sk[j] = a; }
        __syncthreads();
    }
    if (last) {
        for (int i = tid; i < 2048; i += 1024) {
            int gi = base + i;
            if (gi < k) out_idx[gi] = (int)(~(unsigned)(sk[i] & 0xFFFFFFFFu));
        }
    } else {
        for (int i = tid; i < 2048; i += 1024) keys[base + i] = sk[i];
    }
}

__global__ void k_pos2(const int* __restrict__ i2, int* __restrict__ pos2) {
    int r = blockIdx.x * blockDim.x + threadIdx.x;
    if (r < KK1) pos2[i2[r]] = r;
}
__global__ void k_pos3(const int* __restrict__ i2, const int* __restrict__ i4,
                       int* __restrict__ pos3) {
    int q = blockIdx.x * blockDim.x + threadIdx.x;
    if (q < KK2) pos3[i2[i4[q]]] = q;
}
__global__ void k_pos4(const int* __restrict__ i2, const int* __restrict__ i4,
                       const int* __restrict__ i6, int* __restrict__ pos4) {
    int r = blockIdx.x * blockDim.x + threadIdx.x;
    if (r < KK3) pos4[i2[i4[i6[r]]]] = r;
}

// ---- pooled features: xout[r] = elu(x[idx[r]] * sigmoid(score[idx[r]])) ----
__global__ void k_poolx(const float* __restrict__ x, const float* __restrict__ score,
                        const int* __restrict__ idx, int k, int F, float* __restrict__ xout) {
    int t = blockIdx.x * blockDim.x + threadIdx.x;
    if (t >= k * F) return;
    int r = t / F, f = t - r * F;
    int j = idx[r];
    xout[t] = eluf(x[(size_t)j * F + f] * sigf(score[j]));
}

// ---- unpool scatter (left part of concat), with elu ----
__global__ void k_scat(const float* __restrict__ xin, const int* __restrict__ idx,
                       float* __restrict__ xcat, int k, int Fl, int Fcat) {
    int t = blockIdx.x * blockDim.x + threadIdx.x;
    if (t >= k * Fl) return;
    int r = t / Fl, f = t - r * Fl;
    xcat[(size_t)idx[r] * Fcat + f] = eluf(xin[t]);
}
// ---- right part of concat, with elu ----
__global__ void k_catr(const float* __restrict__ xr, float* __restrict__ xcat,
                       int n, int Fr, int Fcat, int off) {
    int t = blockIdx.x * blockDim.x + threadIdx.x;
    if (t >= n * Fr) return;
    int q = t / Fr, f = t - q * Fr;
    xcat[(size_t)q * Fcat + off + f] = eluf(xr[t]);
}

// ---- segment max/sum/count over batch ----
__global__ void k_seg(const float* __restrict__ x13, const int* __restrict__ batch,
                      unsigned* __restrict__ gmaxu, float* __restrict__ gsum,
                      int* __restrict__ gcnt) {
    int t = blockIdx.x * blockDim.x + threadIdx.x;
    if (t >= NN * 32) return;
    int j = t >> 5, f = t & 31;
    int g = batch[j];
    float v = x13[t];
    atomicMax(&gmaxu[(g << 5) + f], f2s(v));
    atomicAdd(&gsum[(g << 5) + f], v);
    if (f == 0) atomicAdd(&gcnt[g], 1);
}

// ---- head ----
__global__ void k_head(const unsigned* __restrict__ gmaxu, const float* __restrict__ gsum,
                       const int* __restrict__ gcnt, const float* __restrict__ Wl1,
                       const float* __restrict__ Wc, const float* __restrict__ bc,
                       float* __restrict__ out) {
    __shared__ float h0[GG * 64];
    __shared__ float h1[GG * 64];
    __shared__ float lg[GG * CC];
    int tid = threadIdx.x;
    for (int t = tid; t < GG * 64; t += blockDim.x) {
        int g = t >> 6, c = t & 63;
        float v;
        if (c < 32) v = s2f(gmaxu[(g << 5) + c]);
        else v = gsum[(g << 5) + (c - 32)] / (float)gcnt[g];
        h0[t] = eluf(v);
    }
    __syncthreads();
    for (int t = tid; t < GG * 64; t += blockDim.x) {
        int g = t >> 6, j = t & 63;
        float s = 0.f;
        for (int k = 0; k < 64; k++) s += h0[(g << 6) + k] * Wl1[k * 64 + j];
        h1[t] = eluf(s);
    }
    __syncthreads();
    for (int t = tid; t < GG * CC; t += blockDim.x) {
        int g = t / CC, c = t - g * CC;
        float s = bc[c];
        for (int k = 0; k < 64; k++) s += h1[(g << 6) + k] * Wc[k * CC + c];
        lg[t] = s;
    }
    __syncthreads();
    if (tid < GG) {
        int g = tid;
        float m = -1e30f;
        for (int c = 0; c < CC; c++) m = fmaxf(m, lg[g * CC + c]);
        float se = 0.f;
        for (int c = 0; c < CC; c++) se += expf(lg[g * CC + c] - m);
        float lse = m + logf(se);
        for (int c = 0; c < CC; c++) out[g * CC + c] = lg[g * CC + c] - lse;
    }
}

static void run_topk(const float* score, unsigned long long* keys, int n, int k,
                     int* out_idx, hipStream_t stream) {
    int chunks = n >> 11;
    if (n == 2048) {
        k_sort_chunk<<<1, 1024, 0, stream>>>(score, keys, 1, k, out_idx);
        return;
    }
    k_sort_chunk<<<chunks, 1024, 0, stream>>>(score, keys, 0, k, out_idx);
    if (n == 4096) {
        k_gpass<<<(n / 2) / 256, 256, 0, stream>>>(keys, 4096, 2048);
        k_lmerge<<<k >> 11, 1024, 0, stream>>>(keys, 4096, 1, k, out_idx);
    } else { // 8192
        k_gpass<<<(n / 2) / 256, 256, 0, stream>>>(keys, 4096, 2048);
        k_lmerge<<<chunks, 1024, 0, stream>>>(keys, 4096, 0, k, out_idx);
        k_gpass<<<(n / 2) / 256, 256, 0, stream>>>(keys, 8192, 4096);
        k_gpass<<<(n / 2) / 256, 256, 0, stream>>>(keys, 8192, 2048);
        k_lmerge<<<k >> 11, 1024, 0, stream>>>(keys, 8192, 1, k, out_idx);
    }
}

extern "C" void kernel_launch(void* const* d_in, const int* in_sizes, int n_in,
                              void* d_out, int out_size, void* d_ws, size_t ws_size,
                              hipStream_t stream) {
    const float* x = (const float*)d_in[0];
    const int* ei = (const int*)d_in[1];
    const int* batch = (const int*)d_in[2];
    const float* W1 = (const float*)d_in[3];  const float* b1 = (const float*)d_in[4];
    const float* W2 = (const float*)d_in[5];  const float* b2 = (const float*)d_in[6];
    const float* W3 = (const float*)d_in[7];  const float* b3 = (const float*)d_in[8];
    const float* W4 = (const float*)d_in[9];  const float* b4 = (const float*)d_in[10];
    const float* W5 = (const float*)d_in[11]; const float* b5 = (const float*)d_in[12];
    const float* W6 = (const float*)d_in[13]; const float* b6 = (const float*)d_in[14];
    const float* W7 = (const float*)d_in[15]; const float* b7 = (const float*)d_in[16];
    const float* p1 = (const float*)d_in[17];
    const float* p2 = (const float*)d_in[18];
    const float* p3 = (const float*)d_in[19];
    const float* Wl1 = (const float*)d_in[20];
    const float* Wc = (const float*)d_in[21];
    const float* bc = (const float*)d_in[22];
    float* out = (float*)d_out;
    (void)in_sizes; (void)n_in; (void)out_size; (void)ws_size;

    char* w = (char*)d_ws;
    size_t off = 0;
    auto alloc = [&](size_t bytes) -> char* {
        char* p = w + off;
        off = (off + bytes + 255) & ~(size_t)255;
        return p;
    };

    // ---- zero-initialized span ----
    size_t zero_begin = off;
    unsigned* bitmap = (unsigned*)alloc((size_t)NN * NN / 8);       // 8 MB
    int* cnt1 = (int*)alloc(NN * 4);
    int* cnt2 = (int*)alloc(KK1 * 4);
    int* cnt3 = (int*)alloc(KK2 * 4);
    int* cnt4 = (int*)alloc(KK3 * 4);
    int* ecnt2 = (int*)alloc(4);
    int* ecnt3 = (int*)alloc(4);
    int* ecnt4 = (int*)alloc(4);
    unsigned* gmaxu = (unsigned*)alloc(GG * 32 * 4);
    float* gsum = (float*)alloc(GG * 32 * 4);
    int* gcnt = (int*)alloc(GG * 4);
    float* x8 = (float*)alloc((size_t)KK2 * 384 * 4);
    float* x10 = (float*)alloc((size_t)KK1 * 192 * 4);
    float* x12 = (float*)alloc((size_t)NN * 96 * 4);
    size_t zero_len = off - zero_begin;

    // ---- 0xFF-initialized span (pos arrays = -1) ----
    size_t ff_begin = off;
    int* pos2 = (int*)alloc(NN * 4);
    int* pos3 = (int*)alloc(NN * 4);
    int* pos4 = (int*)alloc(NN * 4);
    size_t ff_len = off - ff_begin;

    // ---- uninitialized scratch ----
    unsigned char* rep = (unsigned char*)alloc(EE);
    float* dinv1 = (float*)alloc(NN * 4);
    float* dinv2 = (float*)alloc(KK1 * 4);
    float* dinv3 = (float*)alloc(KK2 * 4);
    float* dinv4 = (float*)alloc(KK3 * 4);
    float* xW = (float*)alloc((size_t)262144 * 4);
    float* acc = (float*)alloc((size_t)262144 * 4);
    float* x1 = (float*)alloc((size_t)NN * 32 * 4);
    float* x2 = (float*)alloc((size_t)KK1 * 32 * 4);
    float* x3 = (float*)alloc((size_t)KK1 * 64 * 4);
    float* x4 = (float*)alloc((size_t)KK2 * 64 * 4);
    float* x5 = (float*)alloc((size_t)KK2 * 128 * 4);
    float* x6 = (float*)alloc((size_t)KK3 * 128 * 4);
    float* x7 = (float*)alloc((size_t)KK3 * 256 * 4);
    float* x9 = (float*)alloc((size_t)KK2 * 128 * 4);
    float* x11 = (float*)alloc((size_t)KK1 * 64 * 4);
    float* x13 = (float*)alloc((size_t)NN * 32 * 4);
    float* score1 = (float*)alloc(NN * 4);
    float* score2 = (float*)alloc(KK1 * 4);
    float* score3 = (float*)alloc(KK2 * 4);
    int* i2 = (int*)alloc(KK1 * 4);
    int* i4 = (int*)alloc(KK2 * 4);
    int* i6 = (int*)alloc(KK3 * 4);
    unsigned long long* keys = (unsigned long long*)alloc((size_t)NN * 8);
    unsigned* elist2 = (unsigned*)alloc((size_t)EE * 4);
    unsigned* elist3 = (unsigned*)alloc((size_t)EE * 4);
    unsigned* elist4 = (unsigned*)alloc((size_t)EE * 4);

    hipMemsetAsync(w + zero_begin, 0, zero_len, stream);
    hipMemsetAsync(w + ff_begin, 0xFF, ff_len, stream);

    const int B = 256;
    // ---- setup ----
    k_edge_init<<<EE / B, B, 0, stream>>>(ei, bitmap, rep, cnt1);
    k_dinv<<<NN / B, B, 0, stream>>>(cnt1, dinv1, NN);

    // ---- gcn1 ----
    k_mm<<<(NN * 32) / B, B, 0, stream>>>(x, W1, xW, dinv1, acc, NN, 128, 32);
    k_prop_l1<<<(EE * 32) / B, B, 0, stream>>>(ei, dinv1, xW, acc, 5);
    k_epi<<<(NN * 32) / B, B, 0, stream>>>(acc, b1, x1, NN * 32, 31);

    // ---- pool1: top-4096 ----
    k_score<<<NN / B, B, 0, stream>>>(x1, p1, NN, 32, score1);
    run_topk(score1, keys, NN, KK1, i2, stream);
    k_pos2<<<KK1 / B, B, 0, stream>>>(i2, pos2);
    k_poolx<<<(KK1 * 32) / B, B, 0, stream>>>(x1, score1, i2, KK1, 32, x2);
    k_compact<<<EE / B, B, 0, stream>>>(ei, rep, pos2, elist2, ecnt2);
    k_deg_pool<<<256, B, 0, stream>>>(elist2, ecnt2, cnt2);
    k_dinv<<<KK1 / B, B, 0, stream>>>(cnt2, dinv2, KK1);

    // ---- gcn2 ----
    k_mm<<<(KK1 * 64) / B, B, 0, stream>>>(x2, W2, xW, dinv2, acc, KK1, 32, 64);
    k_prop_pool<<<1024, B, 0, stream>>>(elist2, ecnt2, dinv2, xW, acc, 6);
    k_epi<<<(KK1 * 64) / B, B, 0, stream>>>(acc, b2, x3, KK1 * 64, 63);

    // ---- pool2: top-2048 ----
    k_score<<<KK1 / B, B, 0, stream>>>(x3, p2, KK1, 64, score2);
    run_topk(score2, keys, KK1, KK2, i4, stream);
    k_pos3<<<KK2 / B, B, 0, stream>>>(i2, i4, pos3);
    k_poolx<<<(KK2 * 64) / B, B, 0, stream>>>(x3, score2, i4, KK2, 64, x4);
    k_compact<<<EE / B, B, 0, stream>>>(ei, rep, pos3, elist3, ecnt3);
    k_deg_pool<<<256, B, 0, stream>>>(elist3, ecnt3, cnt3);
    k_dinv<<<KK2 / B, B, 0, stream>>>(cnt3, dinv3, KK2);

    // ---- gcn3 ----
    k_mm<<<(KK2 * 128) / B, B, 0, stream>>>(x4, W3, xW, dinv3, acc, KK2, 64, 128);
    k_prop_pool<<<1024, B, 0, stream>>>(elist3, ecnt3, dinv3, xW, acc, 7);
    k_epi<<<(KK2 * 128) / B, B, 0, stream>>>(acc, b3, x5, KK2 * 128, 127);

    // ---- pool3: top-1024 ----
    k_score<<<KK2 / B, B, 0, stream>>>(x5, p3, KK2, 128, score3);
    run_topk(score3, keys, KK2, KK3, i6, stream);
    k_pos4<<<KK3 / B, B, 0, stream>>>(i2, i4, i6, pos4);
    k_poolx<<<(KK3 * 128) / B, B, 0, stream>>>(x5, score3, i6, KK3, 128, x6);
    k_compact<<<EE / B, B, 0, stream>>>(ei, rep, pos4, elist4, ecnt4);
    k_deg_pool<<<256, B, 0, stream>>>(elist4, ecnt4, cnt4);
    k_dinv<<<KK3 / B, B, 0, stream>>>(cnt4, dinv4, KK3);

    // ---- gcn4 ----
    k_mm<<<(KK3 * 256) / B, B, 0, stream>>>(x6, W4, xW, dinv4, acc, KK3, 128, 256);
    k_prop_pool<<<1024, B, 0, stream>>>(elist4, ecnt4, dinv4, xW, acc, 8);
    k_epi<<<(KK3 * 256) / B, B, 0, stream>>>(acc, b4, x7, KK3 * 256, 255);

    // ---- unpool -> x8 ----
    k_scat<<<(KK3 * 256) / B, B, 0, stream>>>(x7, i6, x8, KK3, 256, 384);
    k_catr<<<(KK2 * 128) / B, B, 0, stream>>>(x5, x8, KK2, 128, 384, 256);

    // ---- gcn5 ----
    k_mm<<<(KK2 * 128) / B, B, 0, stream>>>(x8, W5, xW, dinv3, acc, KK2, 384, 128);
    k_prop_pool<<<1024, B, 0, stream>>>(elist3, ecnt3, dinv3, xW, acc, 7);
    k_epi<<<(KK2 * 128) / B, B, 0, stream>>>(acc, b5, x9, KK2 * 128, 127);

    // ---- unpool -> x10 ----
    k_scat<<<(KK2 * 128) / B, B, 0, stream>>>(x9, i4, x10, KK2, 128, 192);
    k_catr<<<(KK1 * 64) / B, B, 0, stream>>>(x3, x10, KK1, 64, 192, 128);

    // ---- gcn6 ----
    k_mm<<<(KK1 * 64) / B, B, 0, stream>>>(x10, W6, xW, dinv2, acc, KK1, 192, 64);
    k_prop_pool<<<1024, B, 0, stream>>>(elist2, ecnt2, dinv2, xW, acc, 6);
    k_epi<<<(KK1 * 64) / B, B, 0, stream>>>(acc, b6, x11, KK1 * 64, 63);

    // ---- unpool -> x12 ----
    k_scat<<<(KK1 * 64) / B, B, 0, stream>>>(x11, i2, x12, KK1, 64, 96);
    k_catr<<<(NN * 32) / B, B, 0, stream>>>(x1, x12, NN, 32, 96, 64);

    // ---- gcn7 ----
    k_mm<<<(NN * 32) / B, B, 0, stream>>>(x12, W7, xW, dinv1, acc, NN, 96, 32);
    k_prop_l1<<<(EE * 32) / B, B, 0, stream>>>(ei, dinv1, xW, acc, 5);
    k_epi<<<(NN * 32) / B, B, 0, stream>>>(acc, b7, x13, NN * 32, 31);

    // ---- readout ----
    k_seg<<<(NN * 32) / B, B, 0, stream>>>(x13, batch, gmaxu, gsum, gcnt);
    k_head<<<1, 1024, 0, stream>>>(gmaxu, gsum, gcnt, Wl1, Wc, bc, out);
}

// Round 3
// 586.402 us; speedup vs baseline: 1.5078x; 1.2167x over previous
//
#include <hip/hip_runtime.h>
#include <math.h>

#define NN 8192
#define EE 262144
#define GG 64
#define CC 10
#define KK1 4096
#define KK2 2048
#define KK3 1024

__device__ __forceinline__ float eluf(float x) { return x > 0.f ? x : expm1f(x); }
__device__ __forceinline__ float sigf(float x) { return 1.f / (1.f + expf(-x)); }
__device__ __forceinline__ unsigned f2s(float f) {
    unsigned u = __float_as_uint(f);
    return (u & 0x80000000u) ? ~u : (u | 0x80000000u);
}
__device__ __forceinline__ float s2f(unsigned u) {
    return (u & 0x80000000u) ? __uint_as_float(u ^ 0x80000000u) : __uint_as_float(~u);
}

// ---- edge init: dedup representative flag + weighted in-degree (level 1) ----
__global__ void k_edge_init(const int* __restrict__ ei, unsigned* __restrict__ bitmap,
                            unsigned char* __restrict__ rep, int* __restrict__ cnt1) {
    int e = blockIdx.x * blockDim.x + threadIdx.x;
    if (e >= EE) return;
    int s = ei[e], d = ei[EE + e];
    unsigned key = ((unsigned)s << 13) | (unsigned)d;   // N = 8192 = 2^13
    unsigned old = atomicOr(&bitmap[key >> 5], 1u << (key & 31u));
    rep[e] = ((old >> (key & 31u)) & 1u) ? 0 : 1;
    atomicAdd(&cnt1[d], 1);
}

__global__ void k_dinv(const int* __restrict__ cnt, float* __restrict__ dinv, int n) {
    int j = blockIdx.x * blockDim.x + threadIdx.x;
    if (j < n) dinv[j] = 1.f / sqrtf((float)(cnt[j] + 1));
}

// ---- exclusive prefix scan over n<=8192 counts -> rowstart[n+1] and cursor copy ----
__global__ void k_prefix(const int* __restrict__ cnt, int* __restrict__ rs,
                         int* __restrict__ cur, int n) {
    __shared__ int ts[1024];
    int tid = threadIdx.x;
    int ept = n >> 10;                 // 1,2,4,8
    int base = tid * ept;
    int local[8];
    int s = 0;
    for (int i = 0; i < ept; i++) { local[i] = cnt[base + i]; s += local[i]; }
    ts[tid] = s;
    __syncthreads();
    for (int off = 1; off < 1024; off <<= 1) {
        int v = ts[tid];
        int add = (tid >= off) ? ts[tid - off] : 0;
        __syncthreads();
        ts[tid] = v + add;
        __syncthreads();
    }
    int run = (tid == 0) ? 0 : ts[tid - 1];
    for (int i = 0; i < ept; i++) { rs[base + i] = run; cur[base + i] = run; run += local[i]; }
    if (tid == 1023) rs[n] = run;
}

// ---- level-1 CSR scatter: all edges, with multiplicity ----
__global__ void k_csr_l1(const int* __restrict__ ei, int* __restrict__ cur,
                         int* __restrict__ csr) {
    int e = blockIdx.x * blockDim.x + threadIdx.x;
    if (e >= EE) return;
    csr[atomicAdd(&cur[ei[EE + e]], 1)] = ei[e];
}

// ---- pooled level: degree count (dedup'd, both endpoints selected) ----
__global__ void k_deg_lvl(const int* __restrict__ ei, const unsigned char* __restrict__ rep,
                          const int* __restrict__ pos, int* __restrict__ cnt) {
    int e = blockIdx.x * blockDim.x + threadIdx.x;
    if (e >= EE || !rep[e]) return;
    int ps = pos[ei[e]], pd = pos[ei[EE + e]];
    if (ps >= 0 && pd >= 0) atomicAdd(&cnt[pd], 1);
}
// ---- pooled level: CSR scatter ----
__global__ void k_csr_lvl(const int* __restrict__ ei, const unsigned char* __restrict__ rep,
                          const int* __restrict__ pos, int* __restrict__ cur,
                          int* __restrict__ csr) {
    int e = blockIdx.x * blockDim.x + threadIdx.x;
    if (e >= EE || !rep[e]) return;
    int ps = pos[ei[e]], pd = pos[ei[EE + e]];
    if (ps >= 0 && pd >= 0) csr[atomicAdd(&cur[pd], 1)] = ps;
}

// ---- Y[m,f] = sum_k X[m,k]*W[k,f] ----
__global__ void k_mm(const float* __restrict__ X, const float* __restrict__ W,
                     float* __restrict__ Y, int M, int K, int F) {
    int t = blockIdx.x * blockDim.x + threadIdx.x;
    if (t >= M * F) return;
    int m = t / F, f = t - m * F;
    const float* xr = X + (size_t)m * K;
    float s = 0.f;
    for (int k = 0; k < K; k += 4) {
        s += xr[k] * W[k * F + f];
        s += xr[k + 1] * W[(k + 1) * F + f];
        s += xr[k + 2] * W[(k + 2) * F + f];
        s += xr[k + 3] * W[(k + 3) * F + f];
    }
    Y[t] = s;
}

// ---- CSR gather propagate + self term + bias + elu, all fused ----
// x[d,f] = elu( dinv[d]*(dinv[d]*xW[d,f] + sum_s dinv[s]*xW[s,f]) + b[f] )
__global__ void k_prop_csr(const int* __restrict__ csr, const int* __restrict__ rs,
                           const float* __restrict__ dinv, const float* __restrict__ xW,
                           const float* __restrict__ b, float* __restrict__ xout,
                           int n, int logF) {
    int t = blockIdx.x * blockDim.x + threadIdx.x;
    if (t >= (n << logF)) return;
    int d = t >> logF, f = t & ((1 << logF) - 1);
    int j0 = rs[d], j1 = rs[d + 1];
    float dd = dinv[d];
    float sum = dd * xW[t];
    for (int j = j0; j < j1; j++) {
        int s = csr[j];
        sum += dinv[s] * xW[(s << logF) + f];
    }
    xout[t] = eluf(dd * sum + b[f]);
}

// ---- score[r] = dot(x[r], p) / ||p|| ----
__global__ void k_score(const float* __restrict__ x, const float* __restrict__ p,
                        int n, int F, float* __restrict__ score) {
    int r = blockIdx.x * blockDim.x + threadIdx.x;
    if (r >= n) return;
    float nrm = 0.f, dp = 0.f;
    const float* xr = x + (size_t)r * F;
    for (int k = 0; k < F; k++) { nrm += p[k] * p[k]; dp += xr[k] * p[k]; }
    score[r] = dp / sqrtf(nrm);
}

// ==== parallel bitonic top-k (descending, ties -> smaller index; exact jax order) ====
__global__ void k_sort_chunk(const float* __restrict__ score,
                             unsigned long long* __restrict__ keys,
                             int last, int k, int* __restrict__ out_idx) {
    __shared__ unsigned long long sk[2048];
    int base = blockIdx.x << 11;
    int tid = threadIdx.x;
    for (int i = tid; i < 2048; i += 1024) {
        int gi = base + i;
        sk[i] = ((unsigned long long)f2s(score[gi]) << 32) | (unsigned)(~gi);
    }
    __syncthreads();
    for (int sz = 2; sz <= 2048; sz <<= 1) {
        for (int st = sz >> 1; st > 0; st >>= 1) {
            int i = ((tid & ~(st - 1)) << 1) | (tid & (st - 1));
            int j = i | st;
            unsigned long long a = sk[i], b = sk[j];
            bool desc = (((base + i) & sz) == 0);
            if (desc ? (a < b) : (a > b)) { sk[i] = b; sk[j] = a; }
            __syncthreads();
        }
    }
    if (last) {
        for (int i = tid; i < 2048; i += 1024) {
            int gi = base + i;
            if (gi < k) out_idx[gi] = (int)(~(unsigned)(sk[i] & 0xFFFFFFFFu));
        }
    } else {
        for (int i = tid; i < 2048; i += 1024) keys[base + i] = sk[i];
    }
}

__global__ void k_gpass(unsigned long long* __restrict__ keys, int sz, int st) {
    int p = blockIdx.x * blockDim.x + threadIdx.x;
    int i = ((p & ~(st - 1)) << 1) | (p & (st - 1));
    int j = i | st;
    unsigned long long a = keys[i], b = keys[j];
    bool desc = ((i & sz) == 0);
    if (desc ? (a < b) : (a > b)) { keys[i] = b; keys[j] = a; }
}

__global__ void k_lmerge(unsigned long long* __restrict__ keys, int sz,
                         int last, int k, int* __restrict__ out_idx) {
    __shared__ unsigned long long sk[2048];
    int base = blockIdx.x << 11;
    int tid = threadIdx.x;
    for (int i = tid; i < 2048; i += 1024) sk[i] = keys[base + i];
    __syncthreads();
    for (int st = 1024; st > 0; st >>= 1) {
        int i = ((tid & ~(st - 1)) << 1) | (tid & (st - 1));
        int j = i | st;
        unsigned long long a = sk[i], b = sk[j];
        bool desc = (((base + i) & sz) == 0);
        if (desc ? (a < b) : (a > b)) { sk[i] = b; sk[j] = a; }
        __syncthreads();
    }
    if (last) {
        for (int i = tid; i < 2048; i += 1024) {
            int gi = base + i;
            if (gi < k) out_idx[gi] = (int)(~(unsigned)(sk[i] & 0xFFFFFFFFu));
        }
    } else {
        for (int i = tid; i < 2048; i += 1024) keys[base + i] = sk[i];
    }
}

__global__ void k_pos2(const int* __restrict__ i2, int* __restrict__ pos2) {
    int r = blockIdx.x * blockDim.x + threadIdx.x;
    if (r < KK1) pos2[i2[r]] = r;
}
__global__ void k_pos3(const int* __restrict__ i2, const int* __restrict__ i4,
                       int* __restrict__ pos3) {
    int q = blockIdx.x * blockDim.x + threadIdx.x;
    if (q < KK2) pos3[i2[i4[q]]] = q;
}
__global__ void k_pos4(const int* __restrict__ i2, const int* __restrict__ i4,
                       const int* __restrict__ i6, int* __restrict__ pos4) {
    int r = blockIdx.x * blockDim.x + threadIdx.x;
    if (r < KK3) pos4[i2[i4[i6[r]]]] = r;
}

// ---- pooled features: xout[r] = elu(x[idx[r]] * sigmoid(score[idx[r]])) ----
__global__ void k_poolx(const float* __restrict__ x, const float* __restrict__ score,
                        const int* __restrict__ idx, int k, int F, float* __restrict__ xout) {
    int t = blockIdx.x * blockDim.x + threadIdx.x;
    if (t >= k * F) return;
    int r = t / F, f = t - r * F;
    int j = idx[r];
    xout[t] = eluf(x[(size_t)j * F + f] * sigf(score[j]));
}

// ---- unpool scatter (left part of concat), with elu ----
__global__ void k_scat(const float* __restrict__ xin, const int* __restrict__ idx,
                       float* __restrict__ xcat, int k, int Fl, int Fcat) {
    int t = blockIdx.x * blockDim.x + threadIdx.x;
    if (t >= k * Fl) return;
    int r = t / Fl, f = t - r * Fl;
    xcat[(size_t)idx[r] * Fcat + f] = eluf(xin[t]);
}
// ---- right part of concat, with elu ----
__global__ void k_catr(const float* __restrict__ xr, float* __restrict__ xcat,
                       int n, int Fr, int Fcat, int off) {
    int t = blockIdx.x * blockDim.x + threadIdx.x;
    if (t >= n * Fr) return;
    int q = t / Fr, f = t - q * Fr;
    xcat[(size_t)q * Fcat + off + f] = eluf(xr[t]);
}

// ---- segment max/sum/count over batch ----
__global__ void k_seg(const float* __restrict__ x13, const int* __restrict__ batch,
                      unsigned* __restrict__ gmaxu, float* __restrict__ gsum,
                      int* __restrict__ gcnt) {
    int t = blockIdx.x * blockDim.x + threadIdx.x;
    if (t >= NN * 32) return;
    int j = t >> 5, f = t & 31;
    int g = batch[j];
    float v = x13[t];
    atomicMax(&gmaxu[(g << 5) + f], f2s(v));
    atomicAdd(&gsum[(g << 5) + f], v);
    if (f == 0) atomicAdd(&gcnt[g], 1);
}

// ---- head ----
__global__ void k_head(const unsigned* __restrict__ gmaxu, const float* __restrict__ gsum,
                       const int* __restrict__ gcnt, const float* __restrict__ Wl1,
                       const float* __restrict__ Wc, const float* __restrict__ bc,
                       float* __restrict__ out) {
    __shared__ float h0[GG * 64];
    __shared__ float h1[GG * 64];
    __shared__ float lg[GG * CC];
    int tid = threadIdx.x;
    for (int t = tid; t < GG * 64; t += blockDim.x) {
        int g = t >> 6, c = t & 63;
        float v;
        if (c < 32) v = s2f(gmaxu[(g << 5) + c]);
        else v = gsum[(g << 5) + (c - 32)] / (float)gcnt[g];
        h0[t] = eluf(v);
    }
    __syncthreads();
    for (int t = tid; t < GG * 64; t += blockDim.x) {
        int g = t >> 6, j = t & 63;
        float s = 0.f;
        for (int k = 0; k < 64; k++) s += h0[(g << 6) + k] * Wl1[k * 64 + j];
        h1[t] = eluf(s);
    }
    __syncthreads();
    for (int t = tid; t < GG * CC; t += blockDim.x) {
        int g = t / CC, c = t - g * CC;
        float s = bc[c];
        for (int k = 0; k < 64; k++) s += h1[(g << 6) + k] * Wc[k * CC + c];
        lg[t] = s;
    }
    __syncthreads();
    if (tid < GG) {
        int g = tid;
        float m = -1e30f;
        for (int c = 0; c < CC; c++) m = fmaxf(m, lg[g * CC + c]);
        float se = 0.f;
        for (int c = 0; c < CC; c++) se += expf(lg[g * CC + c] - m);
        float lse = m + logf(se);
        for (int c = 0; c < CC; c++) out[g * CC + c] = lg[g * CC + c] - lse;
    }
}

static void run_topk(const float* score, unsigned long long* keys, int n, int k,
                     int* out_idx, hipStream_t stream) {
    int chunks = n >> 11;
    if (n == 2048) {
        k_sort_chunk<<<1, 1024, 0, stream>>>(score, keys, 1, k, out_idx);
        return;
    }
    k_sort_chunk<<<chunks, 1024, 0, stream>>>(score, keys, 0, k, out_idx);
    if (n == 4096) {
        k_gpass<<<(n / 2) / 256, 256, 0, stream>>>(keys, 4096, 2048);
        k_lmerge<<<k >> 11, 1024, 0, stream>>>(keys, 4096, 1, k, out_idx);
    } else { // 8192
        k_gpass<<<(n / 2) / 256, 256, 0, stream>>>(keys, 4096, 2048);
        k_lmerge<<<chunks, 1024, 0, stream>>>(keys, 4096, 0, k, out_idx);
        k_gpass<<<(n / 2) / 256, 256, 0, stream>>>(keys, 8192, 4096);
        k_gpass<<<(n / 2) / 256, 256, 0, stream>>>(keys, 8192, 2048);
        k_lmerge<<<k >> 11, 1024, 0, stream>>>(keys, 8192, 1, k, out_idx);
    }
}

extern "C" void kernel_launch(void* const* d_in, const int* in_sizes, int n_in,
                              void* d_out, int out_size, void* d_ws, size_t ws_size,
                              hipStream_t stream) {
    const float* x = (const float*)d_in[0];
    const int* ei = (const int*)d_in[1];
    const int* batch = (const int*)d_in[2];
    const float* W1 = (const float*)d_in[3];  const float* b1 = (const float*)d_in[4];
    const float* W2 = (const float*)d_in[5];  const float* b2 = (const float*)d_in[6];
    const float* W3 = (const float*)d_in[7];  const float* b3 = (const float*)d_in[8];
    const float* W4 = (const float*)d_in[9];  const float* b4 = (const float*)d_in[10];
    const float* W5 = (const float*)d_in[11]; const float* b5 = (const float*)d_in[12];
    const float* W6 = (const float*)d_in[13]; const float* b6 = (const float*)d_in[14];
    const float* W7 = (const float*)d_in[15]; const float* b7 = (const float*)d_in[16];
    const float* p1 = (const float*)d_in[17];
    const float* p2 = (const float*)d_in[18];
    const float* p3 = (const float*)d_in[19];
    const float* Wl1 = (const float*)d_in[20];
    const float* Wc = (const float*)d_in[21];
    const float* bc = (const float*)d_in[22];
    float* out = (float*)d_out;
    (void)in_sizes; (void)n_in; (void)out_size; (void)ws_size;

    char* w = (char*)d_ws;
    size_t off = 0;
    auto alloc = [&](size_t bytes) -> char* {
        char* p = w + off;
        off = (off + bytes + 255) & ~(size_t)255;
        return p;
    };

    // ---- zero-initialized span ----
    size_t zero_begin = off;
    unsigned* bitmap = (unsigned*)alloc((size_t)NN * NN / 8);       // 8 MB
    int* cnt1 = (int*)alloc(NN * 4);
    int* cnt2 = (int*)alloc(KK1 * 4);
    int* cnt3 = (int*)alloc(KK2 * 4);
    int* cnt4 = (int*)alloc(KK3 * 4);
    unsigned* gmaxu = (unsigned*)alloc(GG * 32 * 4);
    float* gsum = (float*)alloc(GG * 32 * 4);
    int* gcnt = (int*)alloc(GG * 4);
    float* x8 = (float*)alloc((size_t)KK2 * 384 * 4);
    float* x10 = (float*)alloc((size_t)KK1 * 192 * 4);
    float* x12 = (float*)alloc((size_t)NN * 96 * 4);
    size_t zero_len = off - zero_begin;

    // ---- 0xFF-initialized span (pos arrays = -1) ----
    size_t ff_begin = off;
    int* pos2 = (int*)alloc(NN * 4);
    int* pos3 = (int*)alloc(NN * 4);
    int* pos4 = (int*)alloc(NN * 4);
    size_t ff_len = off - ff_begin;

    // ---- uninitialized scratch ----
    unsigned char* rep = (unsigned char*)alloc(EE);
    float* dinv1 = (float*)alloc(NN * 4);
    float* dinv2 = (float*)alloc(KK1 * 4);
    float* dinv3 = (float*)alloc(KK2 * 4);
    float* dinv4 = (float*)alloc(KK3 * 4);
    int* rs1 = (int*)alloc((NN + 1) * 4);  int* cur1 = (int*)alloc(NN * 4);
    int* rs2 = (int*)alloc((KK1 + 1) * 4); int* cur2 = (int*)alloc(KK1 * 4);
    int* rs3 = (int*)alloc((KK2 + 1) * 4); int* cur3 = (int*)alloc(KK2 * 4);
    int* rs4 = (int*)alloc((KK3 + 1) * 4); int* cur4 = (int*)alloc(KK3 * 4);
    int* csr1 = (int*)alloc((size_t)EE * 4);
    int* csr2 = (int*)alloc((size_t)EE * 4);
    int* csr3 = (int*)alloc((size_t)EE * 4);
    int* csr4 = (int*)alloc((size_t)EE * 4);
    float* xW = (float*)alloc((size_t)262144 * 4);
    float* x1 = (float*)alloc((size_t)NN * 32 * 4);
    float* x2 = (float*)alloc((size_t)KK1 * 32 * 4);
    float* x3 = (float*)alloc((size_t)KK1 * 64 * 4);
    float* x4 = (float*)alloc((size_t)KK2 * 64 * 4);
    float* x5 = (float*)alloc((size_t)KK2 * 128 * 4);
    float* x6 = (float*)alloc((size_t)KK3 * 128 * 4);
    float* x7 = (float*)alloc((size_t)KK3 * 256 * 4);
    float* x9 = (float*)alloc((size_t)KK2 * 128 * 4);
    float* x11 = (float*)alloc((size_t)KK1 * 64 * 4);
    float* x13 = (float*)alloc((size_t)NN * 32 * 4);
    float* score1 = (float*)alloc(NN * 4);
    float* score2 = (float*)alloc(KK1 * 4);
    float* score3 = (float*)alloc(KK2 * 4);
    int* i2 = (int*)alloc(KK1 * 4);
    int* i4 = (int*)alloc(KK2 * 4);
    int* i6 = (int*)alloc(KK3 * 4);
    unsigned long long* keys = (unsigned long long*)alloc((size_t)NN * 8);

    hipMemsetAsync(w + zero_begin, 0, zero_len, stream);
    hipMemsetAsync(w + ff_begin, 0xFF, ff_len, stream);

    const int B = 256;
    // ---- setup: dedup flags + weighted level-1 degree; build CSR1 ----
    k_edge_init<<<EE / B, B, 0, stream>>>(ei, bitmap, rep, cnt1);
    k_dinv<<<NN / B, B, 0, stream>>>(cnt1, dinv1, NN);
    k_prefix<<<1, 1024, 0, stream>>>(cnt1, rs1, cur1, NN);
    k_csr_l1<<<EE / B, B, 0, stream>>>(ei, cur1, csr1);

    // ---- gcn1: x1 = elu(gcn(A, x, W1, b1)) ----
    k_mm<<<(NN * 32) / B, B, 0, stream>>>(x, W1, xW, NN, 128, 32);
    k_prop_csr<<<(NN * 32) / B, B, 0, stream>>>(csr1, rs1, dinv1, xW, b1, x1, NN, 5);

    // ---- pool1: top-4096; build CSR2 ----
    k_score<<<NN / B, B, 0, stream>>>(x1, p1, NN, 32, score1);
    run_topk(score1, keys, NN, KK1, i2, stream);
    k_pos2<<<KK1 / B, B, 0, stream>>>(i2, pos2);
    k_poolx<<<(KK1 * 32) / B, B, 0, stream>>>(x1, score1, i2, KK1, 32, x2);
    k_deg_lvl<<<EE / B, B, 0, stream>>>(ei, rep, pos2, cnt2);
    k_dinv<<<KK1 / B, B, 0, stream>>>(cnt2, dinv2, KK1);
    k_prefix<<<1, 1024, 0, stream>>>(cnt2, rs2, cur2, KK1);
    k_csr_lvl<<<EE / B, B, 0, stream>>>(ei, rep, pos2, cur2, csr2);

    // ---- gcn2: x3 ----
    k_mm<<<(KK1 * 64) / B, B, 0, stream>>>(x2, W2, xW, KK1, 32, 64);
    k_prop_csr<<<(KK1 * 64) / B, B, 0, stream>>>(csr2, rs2, dinv2, xW, b2, x3, KK1, 6);

    // ---- pool2: top-2048; build CSR3 ----
    k_score<<<KK1 / B, B, 0, stream>>>(x3, p2, KK1, 64, score2);
    run_topk(score2, keys, KK1, KK2, i4, stream);
    k_pos3<<<KK2 / B, B, 0, stream>>>(i2, i4, pos3);
    k_poolx<<<(KK2 * 64) / B, B, 0, stream>>>(x3, score2, i4, KK2, 64, x4);
    k_deg_lvl<<<EE / B, B, 0, stream>>>(ei, rep, pos3, cnt3);
    k_dinv<<<KK2 / B, B, 0, stream>>>(cnt3, dinv3, KK2);
    k_prefix<<<1, 1024, 0, stream>>>(cnt3, rs3, cur3, KK2);
    k_csr_lvl<<<EE / B, B, 0, stream>>>(ei, rep, pos3, cur3, csr3);

    // ---- gcn3: x5 ----
    k_mm<<<(KK2 * 128) / B, B, 0, stream>>>(x4, W3, xW, KK2, 64, 128);
    k_prop_csr<<<(KK2 * 128) / B, B, 0, stream>>>(csr3, rs3, dinv3, xW, b3, x5, KK2, 7);

    // ---- pool3: top-1024; build CSR4 ----
    k_score<<<KK2 / B, B, 0, stream>>>(x5, p3, KK2, 128, score3);
    run_topk(score3, keys, KK2, KK3, i6, stream);
    k_pos4<<<KK3 / B, B, 0, stream>>>(i2, i4, i6, pos4);
    k_poolx<<<(KK3 * 128) / B, B, 0, stream>>>(x5, score3, i6, KK3, 128, x6);
    k_deg_lvl<<<EE / B, B, 0, stream>>>(ei, rep, pos4, cnt4);
    k_dinv<<<KK3 / B, B, 0, stream>>>(cnt4, dinv4, KK3);
    k_prefix<<<1, 1024, 0, stream>>>(cnt4, rs4, cur4, KK3);
    k_csr_lvl<<<EE / B, B, 0, stream>>>(ei, rep, pos4, cur4, csr4);

    // ---- gcn4: x7 ----
    k_mm<<<(KK3 * 256) / B, B, 0, stream>>>(x6, W4, xW, KK3, 128, 256);
    k_prop_csr<<<(KK3 * 256) / B, B, 0, stream>>>(csr4, rs4, dinv4, xW, b4, x7, KK3, 8);

    // ---- unpool -> x8 ----
    k_scat<<<(KK3 * 256) / B, B, 0, stream>>>(x7, i6, x8, KK3, 256, 384);
    k_catr<<<(KK2 * 128) / B, B, 0, stream>>>(x5, x8, KK2, 128, 384, 256);

    // ---- gcn5: x9 ----
    k_mm<<<(KK2 * 128) / B, B, 0, stream>>>(x8, W5, xW, KK2, 384, 128);
    k_prop_csr<<<(KK2 * 128) / B, B, 0, stream>>>(csr3, rs3, dinv3, xW, b5, x9, KK2, 7);

    // ---- unpool -> x10 ----
    k_scat<<<(KK2 * 128) / B, B, 0, stream>>>(x9, i4, x10, KK2, 128, 192);
    k_catr<<<(KK1 * 64) / B, B, 0, stream>>>(x3, x10, KK1, 64, 192, 128);

    // ---- gcn6: x11 ----
    k_mm<<<(KK1 * 64) / B, B, 0, stream>>>(x10, W6, xW, KK1, 192, 64);
    k_prop_csr<<<(KK1 * 64) / B, B, 0, stream>>>(csr2, rs2, dinv2, xW, b6, x11, KK1, 6);

    // ---- unpool -> x12 ----
    k_scat<<<(KK1 * 64) / B, B, 0, stream>>>(x11, i2, x12, KK1, 64, 96);
    k_catr<<<(NN * 32) / B, B, 0, stream>>>(x1, x12, NN, 32, 96, 64);

    // ---- gcn7: x13 ----
    k_mm<<<(NN * 32) / B, B, 0, stream>>>(x12, W7, xW, NN, 96, 32);
    k_prop_csr<<<(NN * 32) / B, B, 0, stream>>>(csr1, rs1, dinv1, xW, b7, x13, NN, 5);

    // ---- readout ----
    k_seg<<<(NN * 32) / B, B, 0, stream>>>(x13, batch, gmaxu, gsum, gcnt);
    k_head<<<1, 1024, 0, stream>>>(gmaxu, gsum, gcnt, Wl1, Wc, bc, out);
}